// Round 7
// baseline (161.199 us; speedup 1.0000x reference)
//
#include <hip/hip_runtime.h>
#include <hip/hip_bf16.h>
#include <stdint.h>

#define BATCH 4
#define SEQ 1024
#define DMODEL 1024
#define NH 16
#define HD 64

typedef __attribute__((ext_vector_type(8))) short short8;
typedef __attribute__((ext_vector_type(4))) float f32x4;
typedef __attribute__((ext_vector_type(4))) unsigned short ushort4v;

__device__ __forceinline__ unsigned short f2bf(float f) {
    union { float f; uint32_t u; } v; v.f = f;
    uint32_t r = v.u + 0x7fff + ((v.u >> 16) & 1);   // RNE
    return (unsigned short)(r >> 16);
}

__device__ __forceinline__ uint32_t pack2bf(float lo, float hi) {
    return (uint32_t)f2bf(lo) | ((uint32_t)f2bf(hi) << 16);
}

// ---------------- kernel 1: fused prep (cast x -> bf16; transpose W -> Wt bf16) ---------
__global__ __launch_bounds__(256) void prep_kernel(const float* __restrict__ x,
                                                   const float* __restrict__ W,
                                                   unsigned short* __restrict__ xb,
                                                   unsigned short* __restrict__ Wt) {
    __shared__ float tile[32][33];
    int bid = blockIdx.x;
    if (bid < 2048) {
        int t = bid * 256 + threadIdx.x;
        const float4* p = (const float4*)x + (size_t)t * 2;
        float4 a = p[0], b = p[1];
        short8 o;
        o[0] = (short)f2bf(a.x); o[1] = (short)f2bf(a.y);
        o[2] = (short)f2bf(a.z); o[3] = (short)f2bf(a.w);
        o[4] = (short)f2bf(b.x); o[5] = (short)f2bf(b.y);
        o[6] = (short)f2bf(b.z); o[7] = (short)f2bf(b.w);
        *((short8*)xb + t) = o;
    } else {
        int r = bid - 2048;
        int nb = (r % 96) * 32;
        int kb = (r / 96) * 32;
        int tx = threadIdx.x & 31;
        int ty = threadIdx.x >> 5;
#pragma unroll
        for (int i = 0; i < 4; i++) {
            int k = kb + ty + i * 8;
            tile[ty + i * 8][tx] = W[(size_t)k * 3072 + nb + tx];
        }
        __syncthreads();
#pragma unroll
        for (int i = 0; i < 4; i++) {
            int n = nb + ty + i * 8;
            Wt[(size_t)n * 1024 + kb + tx] = f2bf(tile[tx][ty + i * 8]);
        }
    }
}

// ---------------- kernel 3: QKV GEMM (bf16 MFMA, register-prefetch pipeline) ------------
// Staging: global -> VGPR (short8) for tile k+1 issued right after compute barrier of
// tile k -> latency hidden under compute. regs -> LDS at iter top (contiguous b128,
// conflict-free). LDS unpadded with XOR block swizzle (as round 5).
#define BM 128
#define BN 128
#define BKK 64

__global__ __launch_bounds__(256, 3) void qkv_gemm_kernel(
    const unsigned short* __restrict__ xb,   // [4096][1024]
    const unsigned short* __restrict__ wt,   // [3072][1024]
    const float* __restrict__ bias,          // [3072]
    unsigned short* __restrict__ Qb,
    unsigned short* __restrict__ Kb,
    unsigned short* __restrict__ VbT)        // [bh][d][s]
{
    __shared__ __align__(16) unsigned short As[BM][64];
    __shared__ __align__(16) unsigned short Bs[BN][64];
    int tid = threadIdx.x;
    int wave = tid >> 6, lane = tid & 63;
    int quad = lane >> 4, l16 = lane & 15;
    int wm = wave >> 1, wn = wave & 1;
    int m0 = blockIdx.x * BM;
    int n0 = blockIdx.y * BN;

    int grow = lane >> 3;                       // 0..7
    int gcol = ((lane & 7) ^ grow) << 3;        // logical block (global side of swizzle)
    const unsigned short* gA = xb + (size_t)(m0 + wave * 32 + grow) * 1024 + gcol;
    const unsigned short* gB = wt + (size_t)(n0 + wave * 32 + grow) * 1024 + gcol;
    unsigned short* ldsA = &As[wave * 32][0] + lane * 8;   // contiguous 16B/lane
    unsigned short* ldsB = &Bs[wave * 32][0] + lane * 8;
    int sw = l16 & 7;

    short8 areg[4], breg[4];
#pragma unroll
    for (int i = 0; i < 4; i++) {
        areg[i] = *(const short8*)(gA + (size_t)i * 8 * 1024);
        breg[i] = *(const short8*)(gB + (size_t)i * 8 * 1024);
    }

    f32x4 acc[4][4] = {};
    for (int k0 = 0; k0 < 1024; k0 += BKK) {
        __syncthreads();                        // readers of previous tile done
#pragma unroll
        for (int i = 0; i < 4; i++) {
            *(short8*)(ldsA + i * 512) = areg[i];
            *(short8*)(ldsB + i * 512) = breg[i];
        }
        __syncthreads();
        if (k0 + BKK < 1024) {                  // prefetch next tile into regs (flies under compute)
#pragma unroll
            for (int i = 0; i < 4; i++) {
                areg[i] = *(const short8*)(gA + (size_t)i * 8 * 1024 + k0 + BKK);
                breg[i] = *(const short8*)(gB + (size_t)i * 8 * 1024 + k0 + BKK);
            }
        }
#pragma unroll
        for (int kk = 0; kk < BKK; kk += 32) {
            int kb = kk >> 3;
            short8 af[4], bf[4];
#pragma unroll
            for (int t = 0; t < 4; t++) {
                int ar = wm * 64 + t * 16 + l16;
                af[t] = *(const short8*)&As[ar][((kb + quad) ^ sw) << 3];
            }
#pragma unroll
            for (int t = 0; t < 4; t++) {
                int br = wn * 64 + t * 16 + l16;
                bf[t] = *(const short8*)&Bs[br][((kb + quad) ^ sw) << 3];
            }
#pragma unroll
            for (int mt = 0; mt < 4; mt++)
#pragma unroll
                for (int nt = 0; nt < 4; nt++)
                    acc[mt][nt] = __builtin_amdgcn_mfma_f32_16x16x32_bf16(
                        af[mt], bf[nt], acc[mt][nt], 0, 0, 0);
        }
    }
#pragma unroll
    for (int nt = 0; nt < 4; nt++) {
        int n = n0 + wn * 64 + nt * 16 + l16;
        int h = n / 192;
        int c = n - h * 192;
        int which = c >> 6;
        int d = c & 63;
        float bv = bias[n];
        if (which == 2) {
            // V: lane writes 4 consecutive s at fixed d -> vectorized ushort4 store
#pragma unroll
            for (int mt = 0; mt < 4; mt++) {
                int m = m0 + wm * 64 + mt * 16 + quad * 4;
                int b = m >> 10, s = m & 1023;
                ushort4v o;
                o[0] = f2bf(acc[mt][nt][0] + bv);
                o[1] = f2bf(acc[mt][nt][1] + bv);
                o[2] = f2bf(acc[mt][nt][2] + bv);
                o[3] = f2bf(acc[mt][nt][3] + bv);
                *(ushort4v*)&VbT[((size_t)((b * 16 + h) * 64 + d)) * 1024 + s] = o;
            }
        } else {
            unsigned short* dst = (which == 0) ? Qb : Kb;
            float sc = (which == 0) ? 0.125f : 1.0f;
#pragma unroll
            for (int mt = 0; mt < 4; mt++) {
#pragma unroll
                for (int r = 0; r < 4; r++) {
                    int m = m0 + wm * 64 + mt * 16 + quad * 4 + r;
                    int b = m >> 10, s = m & 1023;
                    dst[((size_t)((b * 16 + h) * 1024 + s)) * 64 + d] = f2bf((acc[mt][nt][r] + bv) * sc);
                }
            }
        }
    }
}

// ---------------- kernel 4: flash attention, S^T + key-perm + register prefetch ----------
#define BQ 128
#define BKV 128

__global__ __launch_bounds__(256, 3) void attn_kernel(
    const unsigned short* __restrict__ Qb,
    const unsigned short* __restrict__ Kb,
    const unsigned short* __restrict__ VbT,
    float* __restrict__ out)
{
    __shared__ unsigned short Qs[BQ][64];
    __shared__ unsigned short Ks[BKV][64];
    __shared__ unsigned short Vts[HD][128];

    int tid = threadIdx.x;
    int wave = tid >> 6, lane = tid & 63;
    int quad = lane >> 4, l16 = lane & 15;

    int id = blockIdx.x;
    int xcd = id & 7, rest = id >> 3;
    int qt = rest & 7, grp = rest >> 3;
    int bh = grp * 8 + xcd;
    int q0 = qt * BQ;

    const unsigned short* Qp = Qb + (size_t)bh * SEQ * HD;
    const unsigned short* Kp = Kb + (size_t)bh * SEQ * HD;
    const unsigned short* Vp = VbT + (size_t)bh * HD * SEQ;   // [d][s]

    int f_q = (l16 & 3) | (((l16 >> 3) & 1) << 2);    // Qs reads
    int f_k = (l16 & 3) | (((l16 >> 2) & 1) << 2);    // Ks reads (krow bit3 = l16 bit2)
    int f_v = l16 & 7;                                 // Vts reads
    int rbase = ((l16 >> 2) << 3) | (l16 & 3);         // key-permutation base row

    // stage Q tile (write before first barrier; first read after second barrier)
#pragma unroll
    for (int i = 0; i < 4; i++) {
        int idx = i * 256 + tid;
        int row = idx >> 3, pb = idx & 7;
        int fr = (row & 3) | (((row >> 3) & 1) << 2);
        int lb = pb ^ fr;
        *(short8*)&Qs[row][pb * 8] = *(const short8*)&Qp[(size_t)(q0 + row) * HD + lb * 8];
    }

    // K/V register prefetch
    short8 kreg[4], vreg[4];
    auto load_tile = [&](int kt) {
#pragma unroll
        for (int i = 0; i < 4; i++) {
            int idx = i * 256 + tid;
            int krow = idx >> 3, kpb = idx & 7;
            int klb = kpb ^ ((krow & 3) | (((krow >> 3) & 1) << 2));
            kreg[i] = *(const short8*)&Kp[(size_t)(kt + krow) * HD + klb * 8];
            int vrow = idx >> 4, vpb = idx & 15;
            int vlb = vpb ^ (vrow & 7);
            vreg[i] = *(const short8*)&Vp[(size_t)vrow * SEQ + kt + vlb * 8];
        }
    };
    load_tile(0);

    f32x4 oacc[2][4] = {};       // O^T: [g][d-block]; col q = q0 + wave*32 + g*16 + l16
    float lsum[2] = {0.f, 0.f};

    for (int kt = 0; kt < SEQ; kt += BKV) {
        __syncthreads();
        // regs -> LDS (contiguous 16B/lane, conflict-free)
#pragma unroll
        for (int i = 0; i < 4; i++) {
            int idx = i * 256 + tid;
            int krow = idx >> 3, kpb = idx & 7;
            *(short8*)&Ks[krow][kpb * 8] = kreg[i];
            int vrow = idx >> 4, vpb = idx & 15;
            *(short8*)&Vts[vrow][vpb * 8] = vreg[i];
        }
        __syncthreads();
        if (kt + BKV < SEQ) load_tile(kt + BKV);   // flies under compute

        // S^T: 8 key-tiles x 2 q-groups
        f32x4 sacc[2][8] = {};
#pragma unroll
        for (int ds_ = 0; ds_ < HD; ds_ += 32) {
            int k0b = ds_ >> 3;
            short8 qf[2];
#pragma unroll
            for (int g = 0; g < 2; g++)
                qf[g] = *(const short8*)&Qs[wave * 32 + g * 16 + l16][((k0b + quad) ^ f_q) * 8];
#pragma unroll
            for (int nt = 0; nt < 8; nt++) {
                int krow = rbase + ((nt >> 1) << 5) + ((nt & 1) << 2);
                short8 kf = *(const short8*)&Ks[krow][((k0b + quad) ^ f_k) * 8];
#pragma unroll
                for (int g = 0; g < 2; g++)
                    sacc[g][nt] = __builtin_amdgcn_mfma_f32_16x16x32_bf16(kf, qf[g], sacc[g][nt], 0, 0, 0);
            }
        }

        // unshifted softmax numerators, packed straight into B-frag register order
        uint32_t u[2][8][2];
#pragma unroll
        for (int g = 0; g < 2; g++)
#pragma unroll
            for (int nt = 0; nt < 8; nt++) {
                float p0 = __expf(sacc[g][nt][0]);
                float p1 = __expf(sacc[g][nt][1]);
                float p2 = __expf(sacc[g][nt][2]);
                float p3 = __expf(sacc[g][nt][3]);
                lsum[g] += (p0 + p1) + (p2 + p3);
                u[g][nt][0] = pack2bf(p0, p1);
                u[g][nt][1] = pack2bf(p2, p3);
            }

        // PV: O^T += V^T . P^T  (zero cross-lane ops by construction)
#pragma unroll
        for (int c = 0; c < 4; c++) {
            short8 vf[4];
#pragma unroll
            for (int nt = 0; nt < 4; nt++)
                vf[nt] = *(const short8*)&Vts[nt * 16 + l16][(((c << 2) + quad) ^ f_v) * 8];
#pragma unroll
            for (int g = 0; g < 2; g++) {
                union { uint32_t w[4]; short8 s; } pf;
                pf.w[0] = u[g][2 * c][0];
                pf.w[1] = u[g][2 * c][1];
                pf.w[2] = u[g][2 * c + 1][0];
                pf.w[3] = u[g][2 * c + 1][1];
#pragma unroll
                for (int nt = 0; nt < 4; nt++)
                    oacc[g][nt] = __builtin_amdgcn_mfma_f32_16x16x32_bf16(vf[nt], pf.s, oacc[g][nt], 0, 0, 0);
            }
        }
    }

    // denominators: each quad summed a disjoint key subset
#pragma unroll
    for (int g = 0; g < 2; g++) {
        lsum[g] += __shfl_xor(lsum[g], 16, 64);
        lsum[g] += __shfl_xor(lsum[g], 32, 64);
    }

    int b = bh >> 4, h = bh & 15;
#pragma unroll
    for (int g = 0; g < 2; g++) {
        float inv = 1.f / lsum[g];
        int s = q0 + wave * 32 + g * 16 + l16;
#pragma unroll
        for (int nt = 0; nt < 4; nt++) {
            float4 o;
            o.x = oacc[g][nt][0] * inv;
            o.y = oacc[g][nt][1] * inv;
            o.z = oacc[g][nt][2] * inv;
            o.w = oacc[g][nt][3] * inv;
            *(float4*)&out[(size_t)(b * SEQ + s) * DMODEL + h * HD + nt * 16 + quad * 4] = o;
        }
    }
}

// ---------------- launch ----------------
extern "C" void kernel_launch(void* const* d_in, const int* in_sizes, int n_in,
                              void* d_out, int out_size, void* d_ws, size_t ws_size,
                              hipStream_t stream) {
    const float* x    = (const float*)d_in[0];
    const float* W    = (const float*)d_in[1];
    const float* bias = (const float*)d_in[2];
    float* out = (float*)d_out;
    char* ws = (char*)d_ws;

    unsigned short* xb  = (unsigned short*)(ws);
    unsigned short* wt  = (unsigned short*)(ws + 8388608);
    unsigned short* Qb  = (unsigned short*)(ws + 14680064);
    unsigned short* Kb  = (unsigned short*)(ws + 23068672);
    unsigned short* VbT = (unsigned short*)(ws + 31457280);

    prep_kernel<<<5120, 256, 0, stream>>>(x, W, xb, wt);
    dim3 gg(32, 24);
    qkv_gemm_kernel<<<gg, 256, 0, stream>>>(xb, wt, bias, Qb, Kb, VbT);
    attn_kernel<<<512, 256, 0, stream>>>(Qb, Kb, VbT, out);
}

// Round 8
// 161.014 us; speedup vs baseline: 1.0011x; 1.0011x over previous
//
#include <hip/hip_runtime.h>
#include <hip/hip_bf16.h>
#include <stdint.h>

#define BATCH 4
#define SEQ 1024
#define DMODEL 1024
#define NH 16
#define HD 64

typedef __attribute__((ext_vector_type(8))) short short8;
typedef __attribute__((ext_vector_type(4))) float f32x4;
typedef __attribute__((ext_vector_type(4))) unsigned short ushort4v;

__device__ __forceinline__ unsigned short f2bf(float f) {
    union { float f; uint32_t u; } v; v.f = f;
    uint32_t r = v.u + 0x7fff + ((v.u >> 16) & 1);   // RNE
    return (unsigned short)(r >> 16);
}

__device__ __forceinline__ uint32_t pack2bf(float lo, float hi) {
    return (uint32_t)f2bf(lo) | ((uint32_t)f2bf(hi) << 16);
}

// ---------------- kernel 1: fused prep (cast x -> bf16; transpose W -> Wt bf16) ---------
__global__ __launch_bounds__(256) void prep_kernel(const float* __restrict__ x,
                                                   const float* __restrict__ W,
                                                   unsigned short* __restrict__ xb,
                                                   unsigned short* __restrict__ Wt) {
    __shared__ float tile[32][33];
    int bid = blockIdx.x;
    if (bid < 2048) {
        int t = bid * 256 + threadIdx.x;
        const float4* p = (const float4*)x + (size_t)t * 2;
        float4 a = p[0], b = p[1];
        short8 o;
        o[0] = (short)f2bf(a.x); o[1] = (short)f2bf(a.y);
        o[2] = (short)f2bf(a.z); o[3] = (short)f2bf(a.w);
        o[4] = (short)f2bf(b.x); o[5] = (short)f2bf(b.y);
        o[6] = (short)f2bf(b.z); o[7] = (short)f2bf(b.w);
        *((short8*)xb + t) = o;
    } else {
        int r = bid - 2048;
        int nb = (r % 96) * 32;
        int kb = (r / 96) * 32;
        int tx = threadIdx.x & 31;
        int ty = threadIdx.x >> 5;
#pragma unroll
        for (int i = 0; i < 4; i++) {
            int k = kb + ty + i * 8;
            tile[ty + i * 8][tx] = W[(size_t)k * 3072 + nb + tx];
        }
        __syncthreads();
#pragma unroll
        for (int i = 0; i < 4; i++) {
            int n = nb + ty + i * 8;
            Wt[(size_t)n * 1024 + kb + tx] = f2bf(tile[tx][ty + i * 8]);
        }
    }
}

// ---------------- kernel 3: QKV GEMM (bf16 MFMA, register-prefetch pipeline) ------------
#define BM 128
#define BN 128
#define BKK 64

__global__ __launch_bounds__(256, 3) void qkv_gemm_kernel(
    const unsigned short* __restrict__ xb,   // [4096][1024]
    const unsigned short* __restrict__ wt,   // [3072][1024]
    const float* __restrict__ bias,          // [3072]
    unsigned short* __restrict__ Qb,
    unsigned short* __restrict__ Kb,
    unsigned short* __restrict__ VbT)        // [bh][d][s]
{
    __shared__ __align__(16) unsigned short As[BM][64];
    __shared__ __align__(16) unsigned short Bs[BN][64];
    int tid = threadIdx.x;
    int wave = tid >> 6, lane = tid & 63;
    int quad = lane >> 4, l16 = lane & 15;
    int wm = wave >> 1, wn = wave & 1;
    int m0 = blockIdx.x * BM;
    int n0 = blockIdx.y * BN;

    int grow = lane >> 3;                       // 0..7
    int gcol = ((lane & 7) ^ grow) << 3;        // logical block (global side of swizzle)
    const unsigned short* gA = xb + (size_t)(m0 + wave * 32 + grow) * 1024 + gcol;
    const unsigned short* gB = wt + (size_t)(n0 + wave * 32 + grow) * 1024 + gcol;
    unsigned short* ldsA = &As[wave * 32][0] + lane * 8;   // contiguous 16B/lane
    unsigned short* ldsB = &Bs[wave * 32][0] + lane * 8;
    int sw = l16 & 7;

    short8 areg[4], breg[4];
#pragma unroll
    for (int i = 0; i < 4; i++) {
        areg[i] = *(const short8*)(gA + (size_t)i * 8 * 1024);
        breg[i] = *(const short8*)(gB + (size_t)i * 8 * 1024);
    }

    f32x4 acc[4][4] = {};
    for (int k0 = 0; k0 < 1024; k0 += BKK) {
        __syncthreads();
#pragma unroll
        for (int i = 0; i < 4; i++) {
            *(short8*)(ldsA + i * 512) = areg[i];
            *(short8*)(ldsB + i * 512) = breg[i];
        }
        __syncthreads();
        if (k0 + BKK < 1024) {
#pragma unroll
            for (int i = 0; i < 4; i++) {
                areg[i] = *(const short8*)(gA + (size_t)i * 8 * 1024 + k0 + BKK);
                breg[i] = *(const short8*)(gB + (size_t)i * 8 * 1024 + k0 + BKK);
            }
        }
#pragma unroll
        for (int kk = 0; kk < BKK; kk += 32) {
            int kb = kk >> 3;
            short8 af[4], bf[4];
#pragma unroll
            for (int t = 0; t < 4; t++) {
                int ar = wm * 64 + t * 16 + l16;
                af[t] = *(const short8*)&As[ar][((kb + quad) ^ sw) << 3];
            }
#pragma unroll
            for (int t = 0; t < 4; t++) {
                int br = wn * 64 + t * 16 + l16;
                bf[t] = *(const short8*)&Bs[br][((kb + quad) ^ sw) << 3];
            }
#pragma unroll
            for (int mt = 0; mt < 4; mt++)
#pragma unroll
                for (int nt = 0; nt < 4; nt++)
                    acc[mt][nt] = __builtin_amdgcn_mfma_f32_16x16x32_bf16(
                        af[mt], bf[nt], acc[mt][nt], 0, 0, 0);
        }
    }
#pragma unroll
    for (int nt = 0; nt < 4; nt++) {
        int n = n0 + wn * 64 + nt * 16 + l16;
        int h = n / 192;
        int c = n - h * 192;
        int which = c >> 6;
        int d = c & 63;
        float bv = bias[n];
        if (which == 2) {
#pragma unroll
            for (int mt = 0; mt < 4; mt++) {
                int m = m0 + wm * 64 + mt * 16 + quad * 4;
                int b = m >> 10, s = m & 1023;
                ushort4v o;
                o[0] = f2bf(acc[mt][nt][0] + bv);
                o[1] = f2bf(acc[mt][nt][1] + bv);
                o[2] = f2bf(acc[mt][nt][2] + bv);
                o[3] = f2bf(acc[mt][nt][3] + bv);
                *(ushort4v*)&VbT[((size_t)((b * 16 + h) * 64 + d)) * 1024 + s] = o;
            }
        } else {
            unsigned short* dst = (which == 0) ? Qb : Kb;
            float sc = (which == 0) ? 0.125f : 1.0f;
#pragma unroll
            for (int mt = 0; mt < 4; mt++) {
#pragma unroll
                for (int r = 0; r < 4; r++) {
                    int m = m0 + wm * 64 + mt * 16 + quad * 4 + r;
                    int b = m >> 10, s = m & 1023;
                    dst[((size_t)((b * 16 + h) * 1024 + s)) * 64 + d] = f2bf((acc[mt][nt][r] + bv) * sc);
                }
            }
        }
    }
}

// ---------------- kernel 4: flash attention, chunk-interleaved (spill-free) --------------
// Per 32-key chunk c: S^T for key-tiles 2c,2c+1 -> exp -> PV chunk c. Only 16 sacc regs
// live at once (was 64 -> spilled in round 7). Register prefetch of K/V kept.
#define BQ 128
#define BKV 128

__global__ __launch_bounds__(256, 3) void attn_kernel(
    const unsigned short* __restrict__ Qb,
    const unsigned short* __restrict__ Kb,
    const unsigned short* __restrict__ VbT,
    float* __restrict__ out)
{
    __shared__ unsigned short Qs[BQ][64];
    __shared__ unsigned short Ks[BKV][64];
    __shared__ unsigned short Vts[HD][128];

    int tid = threadIdx.x;
    int wave = tid >> 6, lane = tid & 63;
    int quad = lane >> 4, l16 = lane & 15;

    int id = blockIdx.x;
    int xcd = id & 7, rest = id >> 3;
    int qt = rest & 7, grp = rest >> 3;
    int bh = grp * 8 + xcd;
    int q0 = qt * BQ;

    const unsigned short* Qp = Qb + (size_t)bh * SEQ * HD;
    const unsigned short* Kp = Kb + (size_t)bh * SEQ * HD;
    const unsigned short* Vp = VbT + (size_t)bh * HD * SEQ;   // [d][s]

    int f_q = (l16 & 3) | (((l16 >> 3) & 1) << 2);    // Qs reads (row bit3 = l16 bit3)
    int f_k = (l16 & 3) | (((l16 >> 2) & 1) << 2);    // Ks reads (krow bit3 = l16 bit2)
    int f_v = l16 & 7;                                 // Vts reads
    int rbase = ((l16 >> 2) << 3) | (l16 & 3);         // key-permutation base row

    // stage Q tile
#pragma unroll
    for (int i = 0; i < 4; i++) {
        int idx = i * 256 + tid;
        int row = idx >> 3, pb = idx & 7;
        int fr = (row & 3) | (((row >> 3) & 1) << 2);
        int lb = pb ^ fr;
        *(short8*)&Qs[row][pb * 8] = *(const short8*)&Qp[(size_t)(q0 + row) * HD + lb * 8];
    }

    // K/V register prefetch
    short8 kreg[4], vreg[4];
    auto load_tile = [&](int kt) {
#pragma unroll
        for (int i = 0; i < 4; i++) {
            int idx = i * 256 + tid;
            int krow = idx >> 3, kpb = idx & 7;
            int klb = kpb ^ ((krow & 3) | (((krow >> 3) & 1) << 2));
            kreg[i] = *(const short8*)&Kp[(size_t)(kt + krow) * HD + klb * 8];
            int vrow = idx >> 4, vpb = idx & 15;
            int vlb = vpb ^ (vrow & 7);
            vreg[i] = *(const short8*)&Vp[(size_t)vrow * SEQ + kt + vlb * 8];
        }
    };
    load_tile(0);

    f32x4 oacc[2][4] = {};       // O^T: [g][d-block]; col q = q0 + wave*32 + g*16 + l16
    float lsum[2] = {0.f, 0.f};

    for (int kt = 0; kt < SEQ; kt += BKV) {
        __syncthreads();
#pragma unroll
        for (int i = 0; i < 4; i++) {
            int idx = i * 256 + tid;
            int krow = idx >> 3, kpb = idx & 7;
            *(short8*)&Ks[krow][kpb * 8] = kreg[i];
            int vrow = idx >> 4, vpb = idx & 15;
            *(short8*)&Vts[vrow][vpb * 8] = vreg[i];
        }
        __syncthreads();
        if (kt + BKV < SEQ) load_tile(kt + BKV);   // flies under compute

        // cache Q fragments for this tile (4 LDS reads)
        short8 qf[2][2];
#pragma unroll
        for (int kc = 0; kc < 2; kc++)
#pragma unroll
            for (int g = 0; g < 2; g++)
                qf[g][kc] = *(const short8*)&Qs[wave * 32 + g * 16 + l16][((kc * 4 + quad) ^ f_q) * 8];

        // chunk-interleaved: S^T (tiles 2c,2c+1) -> exp -> PV chunk c
#pragma unroll
        for (int c = 0; c < 4; c++) {
            int base = rbase + (c << 5);
            f32x4 s0[2] = {}, s1[2] = {};
#pragma unroll
            for (int kc = 0; kc < 2; kc++) {
                short8 kf0 = *(const short8*)&Ks[base][((kc * 4 + quad) ^ f_k) * 8];
                short8 kf1 = *(const short8*)&Ks[base + 4][((kc * 4 + quad) ^ f_k) * 8];
#pragma unroll
                for (int g = 0; g < 2; g++) {
                    s0[g] = __builtin_amdgcn_mfma_f32_16x16x32_bf16(kf0, qf[g][kc], s0[g], 0, 0, 0);
                    s1[g] = __builtin_amdgcn_mfma_f32_16x16x32_bf16(kf1, qf[g][kc], s1[g], 0, 0, 0);
                }
            }
            short8 vf[4];
#pragma unroll
            for (int nt = 0; nt < 4; nt++)
                vf[nt] = *(const short8*)&Vts[nt * 16 + l16][(((c << 2) + quad) ^ f_v) * 8];
#pragma unroll
            for (int g = 0; g < 2; g++) {
                float p0 = __expf(s0[g][0]);
                float p1 = __expf(s0[g][1]);
                float p2 = __expf(s0[g][2]);
                float p3 = __expf(s0[g][3]);
                float p4 = __expf(s1[g][0]);
                float p5 = __expf(s1[g][1]);
                float p6 = __expf(s1[g][2]);
                float p7 = __expf(s1[g][3]);
                lsum[g] += ((p0 + p1) + (p2 + p3)) + ((p4 + p5) + (p6 + p7));
                union { uint32_t w[4]; short8 s; } pf;
                pf.w[0] = pack2bf(p0, p1);
                pf.w[1] = pack2bf(p2, p3);
                pf.w[2] = pack2bf(p4, p5);
                pf.w[3] = pack2bf(p6, p7);
#pragma unroll
                for (int nt = 0; nt < 4; nt++)
                    oacc[g][nt] = __builtin_amdgcn_mfma_f32_16x16x32_bf16(vf[nt], pf.s, oacc[g][nt], 0, 0, 0);
            }
        }
    }

    // denominators: each quad summed a disjoint key subset
#pragma unroll
    for (int g = 0; g < 2; g++) {
        lsum[g] += __shfl_xor(lsum[g], 16, 64);
        lsum[g] += __shfl_xor(lsum[g], 32, 64);
    }

    int b = bh >> 4, h = bh & 15;
#pragma unroll
    for (int g = 0; g < 2; g++) {
        float inv = 1.f / lsum[g];
        int s = q0 + wave * 32 + g * 16 + l16;
#pragma unroll
        for (int nt = 0; nt < 4; nt++) {
            float4 o;
            o.x = oacc[g][nt][0] * inv;
            o.y = oacc[g][nt][1] * inv;
            o.z = oacc[g][nt][2] * inv;
            o.w = oacc[g][nt][3] * inv;
            *(float4*)&out[(size_t)(b * SEQ + s) * DMODEL + h * HD + nt * 16 + quad * 4] = o;
        }
    }
}

// ---------------- launch ----------------
extern "C" void kernel_launch(void* const* d_in, const int* in_sizes, int n_in,
                              void* d_out, int out_size, void* d_ws, size_t ws_size,
                              hipStream_t stream) {
    const float* x    = (const float*)d_in[0];
    const float* W    = (const float*)d_in[1];
    const float* bias = (const float*)d_in[2];
    float* out = (float*)d_out;
    char* ws = (char*)d_ws;

    unsigned short* xb  = (unsigned short*)(ws);
    unsigned short* wt  = (unsigned short*)(ws + 8388608);
    unsigned short* Qb  = (unsigned short*)(ws + 14680064);
    unsigned short* Kb  = (unsigned short*)(ws + 23068672);
    unsigned short* VbT = (unsigned short*)(ws + 31457280);

    prep_kernel<<<5120, 256, 0, stream>>>(x, W, xb, wt);
    dim3 gg(32, 24);
    qkv_gemm_kernel<<<gg, 256, 0, stream>>>(xb, wt, bias, Qb, Kb, VbT);
    attn_kernel<<<512, 256, 0, stream>>>(Qb, Kb, VbT, out);
}

// Round 9
// 145.449 us; speedup vs baseline: 1.1083x; 1.1070x over previous
//
#include <hip/hip_runtime.h>
#include <hip/hip_bf16.h>
#include <stdint.h>

#define BATCH 4
#define SEQ 1024
#define DMODEL 1024
#define NH 16
#define HD 64

typedef __attribute__((ext_vector_type(8))) short short8;
typedef __attribute__((ext_vector_type(4))) float f32x4;
typedef __attribute__((ext_vector_type(4))) unsigned short ushort4v;

__device__ __forceinline__ unsigned short f2bf(float f) {
    union { float f; uint32_t u; } v; v.f = f;
    uint32_t r = v.u + 0x7fff + ((v.u >> 16) & 1);   // RNE
    return (unsigned short)(r >> 16);
}

__device__ __forceinline__ uint32_t pack2bf(float lo, float hi) {
    union { __hip_bfloat162 h; uint32_t u; } cv;
    cv.h = __float22bfloat162_rn(make_float2(lo, hi));   // v_cvt_pk_bf16_f32
    return cv.u;
}

// ---------------- kernel 1: fused prep (cast x -> bf16; transpose W -> Wt bf16) ---------
__global__ __launch_bounds__(256) void prep_kernel(const float* __restrict__ x,
                                                   const float* __restrict__ W,
                                                   unsigned short* __restrict__ xb,
                                                   unsigned short* __restrict__ Wt) {
    __shared__ float tile[32][33];
    int bid = blockIdx.x;
    if (bid < 2048) {
        int t = bid * 256 + threadIdx.x;
        const float4* p = (const float4*)x + (size_t)t * 2;
        float4 a = p[0], b = p[1];
        short8 o;
        o[0] = (short)f2bf(a.x); o[1] = (short)f2bf(a.y);
        o[2] = (short)f2bf(a.z); o[3] = (short)f2bf(a.w);
        o[4] = (short)f2bf(b.x); o[5] = (short)f2bf(b.y);
        o[6] = (short)f2bf(b.z); o[7] = (short)f2bf(b.w);
        *((short8*)xb + t) = o;
    } else {
        int r = bid - 2048;
        int nb = (r % 96) * 32;
        int kb = (r / 96) * 32;
        int tx = threadIdx.x & 31;
        int ty = threadIdx.x >> 5;
#pragma unroll
        for (int i = 0; i < 4; i++) {
            int k = kb + ty + i * 8;
            tile[ty + i * 8][tx] = W[(size_t)k * 3072 + nb + tx];
        }
        __syncthreads();
#pragma unroll
        for (int i = 0; i < 4; i++) {
            int n = nb + ty + i * 8;
            Wt[(size_t)n * 1024 + kb + tx] = f2bf(tile[tx][ty + i * 8]);
        }
    }
}

// ---------------- kernel 3: QKV GEMM (bf16 MFMA, register-prefetch pipeline) ------------
// Q scale now folds log2(e): scores arrive pre-multiplied for exp2-based softmax.
#define BM 128
#define BN 128
#define BKK 64
#define QSCALE 0.18033688011112042f   // 0.125 * log2(e)

__global__ __launch_bounds__(256, 3) void qkv_gemm_kernel(
    const unsigned short* __restrict__ xb,   // [4096][1024]
    const unsigned short* __restrict__ wt,   // [3072][1024]
    const float* __restrict__ bias,          // [3072]
    unsigned short* __restrict__ Qb,
    unsigned short* __restrict__ Kb,
    unsigned short* __restrict__ VbT)        // [bh][d][s]
{
    __shared__ __align__(16) unsigned short As[BM][64];
    __shared__ __align__(16) unsigned short Bs[BN][64];
    int tid = threadIdx.x;
    int wave = tid >> 6, lane = tid & 63;
    int quad = lane >> 4, l16 = lane & 15;
    int wm = wave >> 1, wn = wave & 1;
    int m0 = blockIdx.x * BM;
    int n0 = blockIdx.y * BN;

    int grow = lane >> 3;
    int gcol = ((lane & 7) ^ grow) << 3;
    const unsigned short* gA = xb + (size_t)(m0 + wave * 32 + grow) * 1024 + gcol;
    const unsigned short* gB = wt + (size_t)(n0 + wave * 32 + grow) * 1024 + gcol;
    unsigned short* ldsA = &As[wave * 32][0] + lane * 8;
    unsigned short* ldsB = &Bs[wave * 32][0] + lane * 8;
    int sw = l16 & 7;

    short8 areg[4], breg[4];
#pragma unroll
    for (int i = 0; i < 4; i++) {
        areg[i] = *(const short8*)(gA + (size_t)i * 8 * 1024);
        breg[i] = *(const short8*)(gB + (size_t)i * 8 * 1024);
    }

    f32x4 acc[4][4] = {};
    for (int k0 = 0; k0 < 1024; k0 += BKK) {
        __syncthreads();
#pragma unroll
        for (int i = 0; i < 4; i++) {
            *(short8*)(ldsA + i * 512) = areg[i];
            *(short8*)(ldsB + i * 512) = breg[i];
        }
        __syncthreads();
        if (k0 + BKK < 1024) {
#pragma unroll
            for (int i = 0; i < 4; i++) {
                areg[i] = *(const short8*)(gA + (size_t)i * 8 * 1024 + k0 + BKK);
                breg[i] = *(const short8*)(gB + (size_t)i * 8 * 1024 + k0 + BKK);
            }
        }
#pragma unroll
        for (int kk = 0; kk < BKK; kk += 32) {
            int kb = kk >> 3;
            short8 af[4], bf[4];
#pragma unroll
            for (int t = 0; t < 4; t++) {
                int ar = wm * 64 + t * 16 + l16;
                af[t] = *(const short8*)&As[ar][((kb + quad) ^ sw) << 3];
            }
#pragma unroll
            for (int t = 0; t < 4; t++) {
                int br = wn * 64 + t * 16 + l16;
                bf[t] = *(const short8*)&Bs[br][((kb + quad) ^ sw) << 3];
            }
#pragma unroll
            for (int mt = 0; mt < 4; mt++)
#pragma unroll
                for (int nt = 0; nt < 4; nt++)
                    acc[mt][nt] = __builtin_amdgcn_mfma_f32_16x16x32_bf16(
                        af[mt], bf[nt], acc[mt][nt], 0, 0, 0);
        }
    }
#pragma unroll
    for (int nt = 0; nt < 4; nt++) {
        int n = n0 + wn * 64 + nt * 16 + l16;
        int h = n / 192;
        int c = n - h * 192;
        int which = c >> 6;
        int d = c & 63;
        float bv = bias[n];
        if (which == 2) {
#pragma unroll
            for (int mt = 0; mt < 4; mt++) {
                int m = m0 + wm * 64 + mt * 16 + quad * 4;
                int b = m >> 10, s = m & 1023;
                ushort4v o;
                o[0] = f2bf(acc[mt][nt][0] + bv);
                o[1] = f2bf(acc[mt][nt][1] + bv);
                o[2] = f2bf(acc[mt][nt][2] + bv);
                o[3] = f2bf(acc[mt][nt][3] + bv);
                *(ushort4v*)&VbT[((size_t)((b * 16 + h) * 64 + d)) * 1024 + s] = o;
            }
        } else {
            unsigned short* dst = (which == 0) ? Qb : Kb;
            float sc = (which == 0) ? QSCALE : 1.0f;
#pragma unroll
            for (int mt = 0; mt < 4; mt++) {
#pragma unroll
                for (int r = 0; r < 4; r++) {
                    int m = m0 + wm * 64 + mt * 16 + quad * 4 + r;
                    int b = m >> 10, s = m & 1023;
                    dst[((size_t)((b * 16 + h) * 1024 + s)) * 64 + d] = f2bf((acc[mt][nt][r] + bv) * sc);
                }
            }
        }
    }
}

// ---------------- kernel 4: flash attention, k-split waves ------------------------------
// BQ=64, BKV=128, grid 1024. Wave w owns keys [w*32, w*32+32) of each tile for ALL 64 q:
//  - Q fragments hoisted into registers ONCE (direct global load, no Qs LDS).
//  - Per tile per wave: only 8 ds_read_b128 (kf 4 + vf 4) feeding 32 MFMAs.
//  - Key permutation kappa(t,m) = (m>>2)*8 + t*4 + (m&3) (+w*32) makes the S^T C-frag
//    land directly in PV B-operand order (zero cross-lane ops).
//  - exp2 softmax (log2e folded into Q), hardware packed bf16 cvt.
//  - Partial O^T/lsum per wave; LDS tree reduction at the end (reuses Ks/Vts space).
#define BQ 64
#define BKV 128

__global__ __launch_bounds__(256, 2) void attn_kernel(
    const unsigned short* __restrict__ Qb,
    const unsigned short* __restrict__ Kb,
    const unsigned short* __restrict__ VbT,
    float* __restrict__ out)
{
    __shared__ __align__(16) char smem[32768];          // Ks 16K | Vts 16K ; aliased by red
    __shared__ float lbuf[4][4][16];                    // lsum partials
    unsigned short (*Ks)[64]  = (unsigned short(*)[64])smem;
    unsigned short (*Vts)[128] = (unsigned short(*)[128])(smem + 16384);
    float* red = (float*)smem;                          // 8192 floats (2 x 4096)

    int tid = threadIdx.x;
    int wave = tid >> 6, lane = tid & 63;
    int quad = lane >> 4, l16 = lane & 15;

    // XCD swizzle: 16 q-tiles of one bh land on one XCD
    int id = blockIdx.x;
    int xcd = id & 7, rest = id >> 3;
    int qt = rest & 15, grp = rest >> 4;
    int bh = grp * 8 + xcd;
    int q0 = qt * BQ;

    const unsigned short* Qp = Qb + (size_t)bh * SEQ * HD;
    const unsigned short* Kp = Kb + (size_t)bh * SEQ * HD;
    const unsigned short* Vp = VbT + (size_t)bh * HD * SEQ;   // [d][s]

    int f_k = (l16 & 3) | (((l16 >> 2) & 1) << 2);    // = staged swizzle of permuted K rows
    int f_v = l16 & 7;
    int krow0 = (wave << 5) + ((l16 >> 2) << 3) + (l16 & 3);   // kappa(t=0) row in Ks

    // Q fragments hoisted: q = q0 + g*16 + l16, d = kc*32 + quad*8 .. +7
    short8 qf[4][2];
#pragma unroll
    for (int g = 0; g < 4; g++)
#pragma unroll
        for (int kc = 0; kc < 2; kc++)
            qf[g][kc] = *(const short8*)&Qp[(size_t)(q0 + g * 16 + l16) * HD + kc * 32 + quad * 8];

    f32x4 oacc[4][4] = {};      // [g][nt]: O^T row d = nt*16+quad*4+r, col q = q0+g*16+l16
    float lsum[4] = {0.f, 0.f, 0.f, 0.f};

    for (int kt = 0; kt < SEQ; kt += BKV) {
        __syncthreads();
        // stage K [128][8blk] + V^T [64][16blk], inline, swizzled
#pragma unroll
        for (int i = 0; i < 4; i++) {
            int idx = i * 256 + tid;
            int krow = idx >> 3, kpb = idx & 7;
            int klb = kpb ^ ((krow & 3) | (((krow >> 3) & 1) << 2));
            *(short8*)&Ks[krow][kpb * 8] = *(const short8*)&Kp[(size_t)(kt + krow) * HD + klb * 8];
            int vrow = idx >> 4, vpb = idx & 15;
            int vlb = vpb ^ (vrow & 7);
            *(short8*)&Vts[vrow][vpb * 8] = *(const short8*)&Vp[(size_t)vrow * SEQ + kt + vlb * 8];
        }
        __syncthreads();

        // per-tile fragments: kf[t][kc] (4 reads), vf[nt] (4 reads) — shared across all g
        short8 kf[2][2], vf[4];
#pragma unroll
        for (int t = 0; t < 2; t++)
#pragma unroll
            for (int kc = 0; kc < 2; kc++)
                kf[t][kc] = *(const short8*)&Ks[krow0 + t * 4][(((kc << 2) + quad) ^ f_k) * 8];
#pragma unroll
        for (int nt = 0; nt < 4; nt++)
            vf[nt] = *(const short8*)&Vts[nt * 16 + l16][(((wave << 2) + quad) ^ f_v) * 8];

#pragma unroll
        for (int g = 0; g < 4; g++) {
            f32x4 s0 = {}, s1 = {};
#pragma unroll
            for (int kc = 0; kc < 2; kc++) {
                s0 = __builtin_amdgcn_mfma_f32_16x16x32_bf16(kf[0][kc], qf[g][kc], s0, 0, 0, 0);
                s1 = __builtin_amdgcn_mfma_f32_16x16x32_bf16(kf[1][kc], qf[g][kc], s1, 0, 0, 0);
            }
            // exp2 softmax numerators (scores pre-scaled by log2e)
            float p0 = __builtin_amdgcn_exp2f(s0[0]);
            float p1 = __builtin_amdgcn_exp2f(s0[1]);
            float p2 = __builtin_amdgcn_exp2f(s0[2]);
            float p3 = __builtin_amdgcn_exp2f(s0[3]);
            float p4 = __builtin_amdgcn_exp2f(s1[0]);
            float p5 = __builtin_amdgcn_exp2f(s1[1]);
            float p6 = __builtin_amdgcn_exp2f(s1[2]);
            float p7 = __builtin_amdgcn_exp2f(s1[3]);
            lsum[g] += ((p0 + p1) + (p2 + p3)) + ((p4 + p5) + (p6 + p7));
            union { uint32_t w[4]; short8 s; } pf;
            pf.w[0] = pack2bf(p0, p1);     // keys quad*8+0,1
            pf.w[1] = pack2bf(p2, p3);     // keys quad*8+2,3
            pf.w[2] = pack2bf(p4, p5);     // keys quad*8+4,5
            pf.w[3] = pack2bf(p6, p7);     // keys quad*8+6,7
#pragma unroll
            for (int nt = 0; nt < 4; nt++)
                oacc[g][nt] = __builtin_amdgcn_mfma_f32_16x16x32_bf16(vf[nt], pf.s, oacc[g][nt], 0, 0, 0);
        }
    }

    // ---- cross-wave reduction ----
#pragma unroll
    for (int g = 0; g < 4; g++) {            // quad-reduce lsum (keys split by quad too)
        lsum[g] += __shfl_xor(lsum[g], 16, 64);
        lsum[g] += __shfl_xor(lsum[g], 32, 64);
    }
    int off = quad * 16 + l16;
    __syncthreads();                          // Ks/Vts dead -> red
    if (wave >= 2) {
        float* r = red + (wave - 2) * 4096;
#pragma unroll
        for (int g = 0; g < 4; g++)
#pragma unroll
            for (int nt = 0; nt < 4; nt++)
#pragma unroll
                for (int rr = 0; rr < 4; rr++)
                    r[((g * 4 + nt) * 4 + rr) * 64 + off] = oacc[g][nt][rr];
        if (quad == 0)
#pragma unroll
            for (int g = 0; g < 4; g++) lbuf[wave][g][l16] = lsum[g];
    }
    __syncthreads();
    if (wave < 2) {
        float* r = red + wave * 4096;
#pragma unroll
        for (int g = 0; g < 4; g++) {
#pragma unroll
            for (int nt = 0; nt < 4; nt++)
#pragma unroll
                for (int rr = 0; rr < 4; rr++)
                    oacc[g][nt][rr] += r[((g * 4 + nt) * 4 + rr) * 64 + off];
            lsum[g] += lbuf[wave + 2][g][l16];
        }
    }
    __syncthreads();
    if (wave == 1) {
#pragma unroll
        for (int g = 0; g < 4; g++)
#pragma unroll
            for (int nt = 0; nt < 4; nt++)
#pragma unroll
                for (int rr = 0; rr < 4; rr++)
                    red[((g * 4 + nt) * 4 + rr) * 64 + off] = oacc[g][nt][rr];
        if (quad == 0)
#pragma unroll
            for (int g = 0; g < 4; g++) lbuf[1][g][l16] = lsum[g];
    }
    __syncthreads();
    if (wave == 0) {
        int b = bh >> 4, h = bh & 15;
#pragma unroll
        for (int g = 0; g < 4; g++) {
            float l = lsum[g] + lbuf[1][g][l16];
            float inv = 1.f / l;
            int s = q0 + g * 16 + l16;
#pragma unroll
            for (int nt = 0; nt < 4; nt++) {
                float4 o;
                o.x = (oacc[g][nt][0] + red[((g * 4 + nt) * 4 + 0) * 64 + off]) * inv;
                o.y = (oacc[g][nt][1] + red[((g * 4 + nt) * 4 + 1) * 64 + off]) * inv;
                o.z = (oacc[g][nt][2] + red[((g * 4 + nt) * 4 + 2) * 64 + off]) * inv;
                o.w = (oacc[g][nt][3] + red[((g * 4 + nt) * 4 + 3) * 64 + off]) * inv;
                *(float4*)&out[(size_t)(b * SEQ + s) * DMODEL + h * HD + nt * 16 + quad * 4] = o;
            }
        }
    }
}

// ---------------- launch ----------------
extern "C" void kernel_launch(void* const* d_in, const int* in_sizes, int n_in,
                              void* d_out, int out_size, void* d_ws, size_t ws_size,
                              hipStream_t stream) {
    const float* x    = (const float*)d_in[0];
    const float* W    = (const float*)d_in[1];
    const float* bias = (const float*)d_in[2];
    float* out = (float*)d_out;
    char* ws = (char*)d_ws;

    unsigned short* xb  = (unsigned short*)(ws);
    unsigned short* wt  = (unsigned short*)(ws + 8388608);
    unsigned short* Qb  = (unsigned short*)(ws + 14680064);
    unsigned short* Kb  = (unsigned short*)(ws + 23068672);
    unsigned short* VbT = (unsigned short*)(ws + 31457280);

    prep_kernel<<<5120, 256, 0, stream>>>(x, W, xb, wt);
    dim3 gg(32, 24);
    qkv_gemm_kernel<<<gg, 256, 0, stream>>>(xb, wt, bias, Qb, Kb, VbT);
    attn_kernel<<<1024, 256, 0, stream>>>(Qb, Kb, VbT, out);   // 16 qt x 64 bh
}

// Round 10
// 137.637 us; speedup vs baseline: 1.1712x; 1.0568x over previous
//
#include <hip/hip_runtime.h>
#include <hip/hip_bf16.h>
#include <stdint.h>

#define BATCH 4
#define SEQ 1024
#define DMODEL 1024
#define NH 16
#define HD 64

typedef __attribute__((ext_vector_type(8))) short short8;
typedef __attribute__((ext_vector_type(4))) float f32x4;
typedef __attribute__((ext_vector_type(4))) unsigned short ushort4v;

__device__ __forceinline__ unsigned short f2bf(float f) {
    union { float f; uint32_t u; } v; v.f = f;
    uint32_t r = v.u + 0x7fff + ((v.u >> 16) & 1);   // RNE
    return (unsigned short)(r >> 16);
}

__device__ __forceinline__ uint32_t pack2bf(float lo, float hi) {
    union { __hip_bfloat162 h; uint32_t u; } cv;
    cv.h = __float22bfloat162_rn(make_float2(lo, hi));   // v_cvt_pk_bf16_f32
    return cv.u;
}

// ---------------- kernel 1: fused prep (cast x -> bf16; transpose W -> Wt bf16) ---------
__global__ __launch_bounds__(256) void prep_kernel(const float* __restrict__ x,
                                                   const float* __restrict__ W,
                                                   unsigned short* __restrict__ xb,
                                                   unsigned short* __restrict__ Wt) {
    __shared__ float tile[32][33];
    int bid = blockIdx.x;
    if (bid < 2048) {
        int t = bid * 256 + threadIdx.x;
        const float4* p = (const float4*)x + (size_t)t * 2;
        float4 a = p[0], b = p[1];
        short8 o;
        o[0] = (short)f2bf(a.x); o[1] = (short)f2bf(a.y);
        o[2] = (short)f2bf(a.z); o[3] = (short)f2bf(a.w);
        o[4] = (short)f2bf(b.x); o[5] = (short)f2bf(b.y);
        o[6] = (short)f2bf(b.z); o[7] = (short)f2bf(b.w);
        *((short8*)xb + t) = o;
    } else {
        int r = bid - 2048;
        int nb = (r % 96) * 32;
        int kb = (r / 96) * 32;
        int tx = threadIdx.x & 31;
        int ty = threadIdx.x >> 5;
#pragma unroll
        for (int i = 0; i < 4; i++) {
            int k = kb + ty + i * 8;
            tile[ty + i * 8][tx] = W[(size_t)k * 3072 + nb + tx];
        }
        __syncthreads();
#pragma unroll
        for (int i = 0; i < 4; i++) {
            int n = nb + ty + i * 8;
            Wt[(size_t)n * 1024 + kb + tx] = f2bf(tile[tx][ty + i * 8]);
        }
    }
}

// ---------------- kernel 3: QKV GEMM (bf16 MFMA, register-prefetch pipeline) ------------
// Flat grid 768 with 8m x 12n per-XCD patches (id%8 = XCD): per-XCD L2 working set
// A 2MB + B 3MB (was 1+6 = thrash on the 4MB L2).
#define BM 128
#define BN 128
#define BKK 64
#define QSCALE 0.18033688011112042f   // 0.125 * log2(e)

__global__ __launch_bounds__(256, 3) void qkv_gemm_kernel(
    const unsigned short* __restrict__ xb,   // [4096][1024]
    const unsigned short* __restrict__ wt,   // [3072][1024]
    const float* __restrict__ bias,          // [3072]
    unsigned short* __restrict__ Qb,
    unsigned short* __restrict__ Kb,
    unsigned short* __restrict__ VbT)        // [bh][d][s]
{
    __shared__ __align__(16) unsigned short As[BM][64];
    __shared__ __align__(16) unsigned short Bs[BN][64];
    int tid = threadIdx.x;
    int wave = tid >> 6, lane = tid & 63;
    int quad = lane >> 4, l16 = lane & 15;
    int wm = wave >> 1, wn = wave & 1;

    // XCD patch swizzle: xcd = id&7; m-tile in [(xcd&3)*8, +8), n-tile in [(xcd>>2)*12, +12)
    int id = blockIdx.x;
    int x = id & 7, r = id >> 3;              // r: 0..95
    int m_t = (x & 3) * 8 + (r & 7);
    int n_t = (x >> 2) * 12 + (r >> 3);
    int m0 = m_t * BM;
    int n0 = n_t * BN;

    int grow = lane >> 3;
    int gcol = ((lane & 7) ^ grow) << 3;
    const unsigned short* gA = xb + (size_t)(m0 + wave * 32 + grow) * 1024 + gcol;
    const unsigned short* gB = wt + (size_t)(n0 + wave * 32 + grow) * 1024 + gcol;
    unsigned short* ldsA = &As[wave * 32][0] + lane * 8;
    unsigned short* ldsB = &Bs[wave * 32][0] + lane * 8;
    int sw = l16 & 7;

    short8 areg[4], breg[4];
#pragma unroll
    for (int i = 0; i < 4; i++) {
        areg[i] = *(const short8*)(gA + (size_t)i * 8 * 1024);
        breg[i] = *(const short8*)(gB + (size_t)i * 8 * 1024);
    }

    f32x4 acc[4][4] = {};
    for (int k0 = 0; k0 < 1024; k0 += BKK) {
        __syncthreads();
#pragma unroll
        for (int i = 0; i < 4; i++) {
            *(short8*)(ldsA + i * 512) = areg[i];
            *(short8*)(ldsB + i * 512) = breg[i];
        }
        __syncthreads();
        if (k0 + BKK < 1024) {
#pragma unroll
            for (int i = 0; i < 4; i++) {
                areg[i] = *(const short8*)(gA + (size_t)i * 8 * 1024 + k0 + BKK);
                breg[i] = *(const short8*)(gB + (size_t)i * 8 * 1024 + k0 + BKK);
            }
        }
#pragma unroll
        for (int kk = 0; kk < BKK; kk += 32) {
            int kb = kk >> 3;
            short8 af[4], bf[4];
#pragma unroll
            for (int t = 0; t < 4; t++) {
                int ar = wm * 64 + t * 16 + l16;
                af[t] = *(const short8*)&As[ar][((kb + quad) ^ sw) << 3];
            }
#pragma unroll
            for (int t = 0; t < 4; t++) {
                int br = wn * 64 + t * 16 + l16;
                bf[t] = *(const short8*)&Bs[br][((kb + quad) ^ sw) << 3];
            }
#pragma unroll
            for (int mt = 0; mt < 4; mt++)
#pragma unroll
                for (int nt = 0; nt < 4; nt++)
                    acc[mt][nt] = __builtin_amdgcn_mfma_f32_16x16x32_bf16(
                        af[mt], bf[nt], acc[mt][nt], 0, 0, 0);
        }
    }
#pragma unroll
    for (int nt = 0; nt < 4; nt++) {
        int n = n0 + wn * 64 + nt * 16 + l16;
        int h = n / 192;
        int c = n - h * 192;
        int which = c >> 6;
        int d = c & 63;
        float bv = bias[n];
        if (which == 2) {
#pragma unroll
            for (int mt = 0; mt < 4; mt++) {
                int m = m0 + wm * 64 + mt * 16 + quad * 4;
                int b = m >> 10, s = m & 1023;
                ushort4v o;
                o[0] = f2bf(acc[mt][nt][0] + bv);
                o[1] = f2bf(acc[mt][nt][1] + bv);
                o[2] = f2bf(acc[mt][nt][2] + bv);
                o[3] = f2bf(acc[mt][nt][3] + bv);
                *(ushort4v*)&VbT[((size_t)((b * 16 + h) * 64 + d)) * 1024 + s] = o;
            }
        } else {
            unsigned short* dst = (which == 0) ? Qb : Kb;
            float sc = (which == 0) ? QSCALE : 1.0f;
#pragma unroll
            for (int mt = 0; mt < 4; mt++) {
#pragma unroll
                for (int r2 = 0; r2 < 4; r2++) {
                    int m = m0 + wm * 64 + mt * 16 + quad * 4 + r2;
                    int b = m >> 10, s = m & 1023;
                    dst[((size_t)((b * 16 + h) * 1024 + s)) * 64 + d] = f2bf((acc[mt][nt][r2] + bv) * sc);
                }
            }
        }
    }
}

// ---------------- kernel 4: flash attention, hybrid q/k wave-split ----------------------
// BQ=128, BKV=128, grid 512 (64 bh x 8 qt, XCD-grouped by bh). Wave (qh=w&1, kh=w>>1)
// owns q-half qh (64 q, hoisted in regs) x key-half kh (64 keys) of each tile.
//  - staging per tile (32 KB) now serves 128 q -> HBM/L2 + barrier-waits halved vs r9.
//  - key permutation: key = kh*64 + c*32 + (rho>>2)*8 + (rho&3) (+4 for 2nd S-tile)
//    -> S^T C-frag lands directly in PV B-operand order (zero cross-lane ops).
//  - exp2 softmax (log2e folded into Q scale), packed bf16 cvt.
//  - end: kh=1 waves dump partial O/l through dead Ks/Vts space; kh=0 waves finish.
#define BQ 128
#define BKV 128

__global__ __launch_bounds__(256, 2) void attn_kernel(
    const unsigned short* __restrict__ Qb,
    const unsigned short* __restrict__ Kb,
    const unsigned short* __restrict__ VbT,
    float* __restrict__ out)
{
    __shared__ __align__(16) char smem[32768];          // Ks 16K | Vts 16K ; aliased by red
    __shared__ float lbuf[4][4][16];
    unsigned short (*Ks)[64]   = (unsigned short(*)[64])smem;
    unsigned short (*Vts)[128] = (unsigned short(*)[128])(smem + 16384);
    float* red = (float*)smem;                          // 8192 floats = 2 x 16 KB

    int tid = threadIdx.x;
    int wave = tid >> 6, lane = tid & 63;
    int quad = lane >> 4, l16 = lane & 15;
    int qh = wave & 1, kh = wave >> 1;

    // XCD swizzle: 8 qt blocks of one bh land on one XCD
    int id = blockIdx.x;
    int xcd = id & 7, rest = id >> 3;
    int qt = rest & 7, grp = rest >> 3;
    int bh = grp * 8 + xcd;
    int q0 = qt * BQ;

    const unsigned short* Qp = Qb + (size_t)bh * SEQ * HD;
    const unsigned short* Kp = Kb + (size_t)bh * SEQ * HD;
    const unsigned short* Vp = VbT + (size_t)bh * HD * SEQ;   // [d][s]

    int f_k = (l16 & 3) | (((l16 >> 2) & 1) << 2);    // perm-krow bit3 = l16 bit2
    int f_v = l16 & 7;
    int prow = (kh << 6) + ((l16 >> 2) << 3) + (l16 & 3);   // key-perm base row (+c*32, +4)

    // Q fragments hoisted: q = q0 + qh*64 + g*16 + l16
    short8 qf[4][2];
#pragma unroll
    for (int g = 0; g < 4; g++)
#pragma unroll
        for (int kc = 0; kc < 2; kc++)
            qf[g][kc] = *(const short8*)&Qp[(size_t)(q0 + qh * 64 + g * 16 + l16) * HD + kc * 32 + quad * 8];

    f32x4 oacc[4][4] = {};      // [g][nt]: O^T row d = nt*16+quad*4+rr, col q
    float lsum[4] = {0.f, 0.f, 0.f, 0.f};

    for (int kt = 0; kt < SEQ; kt += BKV) {
        __syncthreads();
        // stage K [128][8blk] + V^T [64][16blk], swizzled (same layout as r9)
#pragma unroll
        for (int i = 0; i < 4; i++) {
            int idx = i * 256 + tid;
            int krow = idx >> 3, kpb = idx & 7;
            int klb = kpb ^ ((krow & 3) | (((krow >> 3) & 1) << 2));
            *(short8*)&Ks[krow][kpb * 8] = *(const short8*)&Kp[(size_t)(kt + krow) * HD + klb * 8];
            int vrow = idx >> 4, vpb = idx & 15;
            int vlb = vpb ^ (vrow & 7);
            *(short8*)&Vts[vrow][vpb * 8] = *(const short8*)&Vp[(size_t)vrow * SEQ + kt + vlb * 8];
        }
        __syncthreads();

#pragma unroll
        for (int c = 0; c < 2; c++) {       // 32-key chunk within the wave's 64 keys
            int base = prow + (c << 5);
            short8 kf0[2], kf1[2];
#pragma unroll
            for (int kc = 0; kc < 2; kc++) {
                kf0[kc] = *(const short8*)&Ks[base][(((kc << 2) + quad) ^ f_k) * 8];
                kf1[kc] = *(const short8*)&Ks[base + 4][(((kc << 2) + quad) ^ f_k) * 8];
            }
            short8 vf[4];
#pragma unroll
            for (int nt = 0; nt < 4; nt++)
                vf[nt] = *(const short8*)&Vts[nt * 16 + l16][(((kh << 3) + (c << 2) + quad) ^ f_v) * 8];
#pragma unroll
            for (int g = 0; g < 4; g++) {
                f32x4 s0 = {}, s1 = {};
#pragma unroll
                for (int kc = 0; kc < 2; kc++) {
                    s0 = __builtin_amdgcn_mfma_f32_16x16x32_bf16(kf0[kc], qf[g][kc], s0, 0, 0, 0);
                    s1 = __builtin_amdgcn_mfma_f32_16x16x32_bf16(kf1[kc], qf[g][kc], s1, 0, 0, 0);
                }
                float p0 = __builtin_amdgcn_exp2f(s0[0]);
                float p1 = __builtin_amdgcn_exp2f(s0[1]);
                float p2 = __builtin_amdgcn_exp2f(s0[2]);
                float p3 = __builtin_amdgcn_exp2f(s0[3]);
                float p4 = __builtin_amdgcn_exp2f(s1[0]);
                float p5 = __builtin_amdgcn_exp2f(s1[1]);
                float p6 = __builtin_amdgcn_exp2f(s1[2]);
                float p7 = __builtin_amdgcn_exp2f(s1[3]);
                lsum[g] += ((p0 + p1) + (p2 + p3)) + ((p4 + p5) + (p6 + p7));
                union { uint32_t w[4]; short8 s; } pf;
                pf.w[0] = pack2bf(p0, p1);
                pf.w[1] = pack2bf(p2, p3);
                pf.w[2] = pack2bf(p4, p5);
                pf.w[3] = pack2bf(p6, p7);
#pragma unroll
                for (int nt = 0; nt < 4; nt++)
                    oacc[g][nt] = __builtin_amdgcn_mfma_f32_16x16x32_bf16(vf[nt], pf.s, oacc[g][nt], 0, 0, 0);
            }
        }
    }

    // ---- cross-wave reduction (kh pairs share q-half) ----
#pragma unroll
    for (int g = 0; g < 4; g++) {            // quad-reduce lsum (keys split by quad)
        lsum[g] += __shfl_xor(lsum[g], 16, 64);
        lsum[g] += __shfl_xor(lsum[g], 32, 64);
    }
    int off = quad * 16 + l16;
    __syncthreads();                          // all waves done with Ks/Vts -> red
    if (kh == 1) {
        float* rp = red + qh * 4096;
#pragma unroll
        for (int g = 0; g < 4; g++)
#pragma unroll
            for (int nt = 0; nt < 4; nt++)
#pragma unroll
                for (int rr = 0; rr < 4; rr++)
                    rp[((g * 4 + nt) * 4 + rr) * 64 + off] = oacc[g][nt][rr];
        if (quad == 0)
#pragma unroll
            for (int g = 0; g < 4; g++) lbuf[wave][g][l16] = lsum[g];
    }
    __syncthreads();
    if (kh == 0) {
        float* rp = red + qh * 4096;
        int b = bh >> 4, h = bh & 15;
#pragma unroll
        for (int g = 0; g < 4; g++) {
            float l = lsum[g] + lbuf[wave + 2][g][l16];
            float inv = 1.f / l;
            int s = q0 + qh * 64 + g * 16 + l16;
#pragma unroll
            for (int nt = 0; nt < 4; nt++) {
                float4 o;
                o.x = (oacc[g][nt][0] + rp[((g * 4 + nt) * 4 + 0) * 64 + off]) * inv;
                o.y = (oacc[g][nt][1] + rp[((g * 4 + nt) * 4 + 1) * 64 + off]) * inv;
                o.z = (oacc[g][nt][2] + rp[((g * 4 + nt) * 4 + 2) * 64 + off]) * inv;
                o.w = (oacc[g][nt][3] + rp[((g * 4 + nt) * 4 + 3) * 64 + off]) * inv;
                *(float4*)&out[(size_t)(b * SEQ + s) * DMODEL + h * HD + nt * 16 + quad * 4] = o;
            }
        }
    }
}

// ---------------- launch ----------------
extern "C" void kernel_launch(void* const* d_in, const int* in_sizes, int n_in,
                              void* d_out, int out_size, void* d_ws, size_t ws_size,
                              hipStream_t stream) {
    const float* x    = (const float*)d_in[0];
    const float* W    = (const float*)d_in[1];
    const float* bias = (const float*)d_in[2];
    float* out = (float*)d_out;
    char* ws = (char*)d_ws;

    unsigned short* xb  = (unsigned short*)(ws);
    unsigned short* wt  = (unsigned short*)(ws + 8388608);
    unsigned short* Qb  = (unsigned short*)(ws + 14680064);
    unsigned short* Kb  = (unsigned short*)(ws + 23068672);
    unsigned short* VbT = (unsigned short*)(ws + 31457280);

    prep_kernel<<<5120, 256, 0, stream>>>(x, W, xb, wt);
    qkv_gemm_kernel<<<768, 256, 0, stream>>>(xb, wt, bias, Qb, Kb, VbT);
    attn_kernel<<<512, 256, 0, stream>>>(Qb, Kb, VbT, out);   // 8 qt x 64 bh
}